// Round 16
// baseline (188.742 us; speedup 1.0000x reference)
//
#include <hip/hip_runtime.h>

#define DEV static __device__ __forceinline__

typedef __attribute__((ext_vector_type(8))) short short8;
typedef __attribute__((ext_vector_type(4))) short short4v;
typedef __attribute__((ext_vector_type(4))) float f32x4;
typedef __attribute__((ext_vector_type(4))) unsigned short ushort4v;
typedef __attribute__((ext_vector_type(4))) float float4v;

#define DM 1024
#define NH 16
#define HD 64
#define SS 2048
#define TOK 8192

DEV unsigned short f2bf(float f) {
  union { float f; unsigned u; } v; v.f = f;
  unsigned r = v.u + 0x7FFFu + ((v.u >> 16) & 1u);
  return (unsigned short)(r >> 16);
}
DEV float bf2f(unsigned short h) {
  union { unsigned u; float f; } v; v.u = ((unsigned)h) << 16;
  return v.f;
}

#define MFMA16x32(a, b, c) __builtin_amdgcn_mfma_f32_16x16x32_bf16((a), (b), (c), 0, 0, 0)

DEV f32x4 mfma_pv(short4v a, short4v b, f32x4 c) {
#if __has_builtin(__builtin_amdgcn_mfma_f32_16x16x16bf16_1k)
  return __builtin_amdgcn_mfma_f32_16x16x16bf16_1k(a, b, c, 0, 0, 0);
#else
  f32x4 d;
  asm("v_mfma_f32_16x16x16_bf16 %0, %1, %2, %3" : "=&v"(d) : "v"(a), "v"(b), "v"(c));
  return d;
#endif
}

DEV void gload_lds16(const unsigned short* g, unsigned short* l) {
  __builtin_amdgcn_global_load_lds(
      (const __attribute__((address_space(1))) void*)g,
      (__attribute__((address_space(3))) void*)l, 16, 0, 0);
}

// ------- fused prep: x cvt + Wqkv cvt + Wo cvt + RoPE tables (one launch) ----
__global__ __launch_bounds__(256) void k_prep(const float* __restrict__ x,
                                              unsigned short* __restrict__ x_bf,
                                              const float* __restrict__ Wqkv,
                                              unsigned short* __restrict__ wqkv_bf,
                                              const float* __restrict__ Wo,
                                              unsigned short* __restrict__ wo_bf,
                                              const int* __restrict__ pos,
                                              float* __restrict__ tc,
                                              float* __restrict__ ts) {
  int blk = blockIdx.x;
  if (blk < 8192) {
    int i = blk * 256 + threadIdx.x;
    float4v v = ((const float4v*)x)[i];
    ushort4v o;
    o[0] = f2bf(v[0]); o[1] = f2bf(v[1]); o[2] = f2bf(v[2]); o[3] = f2bf(v[3]);
    ((ushort4v*)x_bf)[i] = o;
  } else if (blk < 11264) {
    int i = (blk - 8192) * 256 + threadIdx.x;
    float4v v = ((const float4v*)Wqkv)[i];
    ushort4v o;
    o[0] = f2bf(v[0]); o[1] = f2bf(v[1]); o[2] = f2bf(v[2]); o[3] = f2bf(v[3]);
    ((ushort4v*)wqkv_bf)[i] = o;
  } else if (blk < 12288) {
    int i = (blk - 11264) * 256 + threadIdx.x;
    float4v v = ((const float4v*)Wo)[i];
    ushort4v o;
    o[0] = f2bf(v[0]); o[1] = f2bf(v[1]); o[2] = f2bf(v[2]); o[3] = f2bf(v[3]);
    ((ushort4v*)wo_bf)[i] = o;
  } else {
    int i = (blk - 12288) * 256 + threadIdx.x;   // B*S*32 total
    int t = i >> 5, fi = i & 31;
    float p = (float)pos[t];
    float inv = powf(10000.0f, -(float)fi / 32.0f);
    float a = p * inv;
    float sv, cv;
    sincosf(a, &sv, &cv);
    tc[i] = cv;
    ts[i] = sv;
  }
}

// ---------------- bf16 GEMM, B^T layout, 3-stage counted-vmcnt pipeline -----
// (R13/R15-measured-best K-loop: BM=256, BN=128, BK=64, 512 thr, 3 rotating
//  buffers, counted vmcnt(6), 0-conflict LDS, m-chunk XCD swizzle.)
// NEW: transposed epilogue via per-wave fp32 LDS staging (reuses dead Abuf):
//  - thread ends holding row=l16, cols lq*4..+3 -> vector stores along d/n
//  - RoPE pair (d, d+1) becomes lane-local: no shfl, half the table loads
// MODE 0: out0 = fp32 [M][N], float4 C-stores
// MODE 1: qkv scatter + fused RoPE; Q/K stored as 8B ushort4, Vt unchanged
template <int MODE>
__global__ __launch_bounds__(512) void k_gemm3(
    const unsigned short* __restrict__ A, const unsigned short* __restrict__ Bm,
    const float* __restrict__ bias, void* __restrict__ out0, void* __restrict__ out1,
    void* __restrict__ out2, const float* __restrict__ tabc,
    const float* __restrict__ tabs, int M, int N, int K) {
  __shared__ __align__(16) unsigned short Abuf[3][256 * 64];   // 96 KB
  __shared__ __align__(16) unsigned short Bbuf[3][128 * 64];   // 48 KB
  const int tid = threadIdx.x;
  const int wid = tid >> 6, lane = tid & 63;
  const int l16 = lane & 15, lq = lane >> 4;
  const int wr = wid >> 1, wc = wid & 1;
  const int r8 = lane >> 3, c8 = lane & 7;    // staging: row-in-octet, chunk
  const int NT = K >> 6;
  const int sx = l16 & 7;                     // read-side swizzle key

  // m-chunk XCD swizzle (R6): xcd = bid&7 owns contiguous m-range, n-fastest.
  const int gx = N >> 7;
  const int nwg = gx * (M >> 8);
  const int chunk = nwg >> 3;
  const int bid = blockIdx.x;
  const int virt = (bid & 7) * chunk + (bid >> 3);
  const int m0 = (virt / gx) << 8;
  const int n0 = (virt % gx) << 7;

#define STAGE_G3(T, BSEL)                                                           \
  {                                                                                 \
    int k0_ = (T) << 6;                                                             \
    unsigned short* ab_ = Abuf[BSEL];                                               \
    unsigned short* bb_ = Bbuf[BSEL];                                               \
    _Pragma("unroll")                                                               \
    for (int i_ = 0; i_ < 4; ++i_) {                                                \
      int c_ = wid * 4 + i_;                                                        \
      gload_lds16(A + (size_t)(m0 + c_ * 8 + r8) * K + k0_ + ((c8 ^ r8) << 3),      \
                  &ab_[c_ * 512]);                                                  \
    }                                                                               \
    _Pragma("unroll")                                                               \
    for (int i_ = 0; i_ < 2; ++i_) {                                                \
      int c_ = wid * 2 + i_;                                                        \
      gload_lds16(Bm + (size_t)(n0 + c_ * 8 + r8) * K + k0_ + ((c8 ^ r8) << 3),     \
                  &bb_[c_ * 512]);                                                  \
    }                                                                               \
  }

  f32x4 acc[4][4];
#pragma unroll
  for (int i = 0; i < 4; i++)
#pragma unroll
    for (int j = 0; j < 4; j++) acc[i][j] = (f32x4){0.f, 0.f, 0.f, 0.f};

  STAGE_G3(0, 0)
  STAGE_G3(1, 1)
  asm volatile("s_waitcnt vmcnt(6)" ::: "memory");
  __builtin_amdgcn_s_barrier();
  __builtin_amdgcn_sched_barrier(0);

  int cb = 0, sb = 2;
  for (int t = 0; t < NT; ++t) {
    if (t + 2 < NT) STAGE_G3(t + 2, sb)
    const unsigned short* Ab = Abuf[cb];
    const unsigned short* Bb = Bbuf[cb];
#pragma unroll
    for (int kk = 0; kk < 2; ++kk) {
      int sw0 = ((kk * 4 + lq) ^ sx) << 3;
      short8 af[4], bfr[4];
#pragma unroll
      for (int mi = 0; mi < 4; ++mi)
        af[mi] = *(const short8*)&Ab[(wr * 64 + mi * 16 + l16) * 64 + sw0];
#pragma unroll
      for (int ni = 0; ni < 4; ++ni)
        bfr[ni] = *(const short8*)&Bb[(wc * 64 + ni * 16 + l16) * 64 + sw0];
#pragma unroll
      for (int mi = 0; mi < 4; ++mi)
#pragma unroll
        for (int ni = 0; ni < 4; ++ni)
          acc[mi][ni] = MFMA16x32(af[mi], bfr[ni], acc[mi][ni]);
    }
    if (t + 1 < NT) {
      if (t + 3 <= NT) {
        asm volatile("s_waitcnt vmcnt(6)" ::: "memory");
      } else {
        asm volatile("s_waitcnt vmcnt(0)" ::: "memory");
      }
      __builtin_amdgcn_s_barrier();
      __builtin_amdgcn_sched_barrier(0);
    }
    cb = (cb == 2) ? 0 : cb + 1;
    sb = (sb == 2) ? 0 : sb + 1;
  }
#undef STAGE_G3

  // -------- transposed epilogue: Abuf is dead, reuse as fp32 staging --------
  __syncthreads();                              // all K-loop LDS reads done
  float* ep = ((float*)Abuf) + wid * 1088;      // per-wave [16][68] fp32

  if (MODE == 0) {
    float* C = (float*)out0;
#pragma unroll
    for (int mi = 0; mi < 4; ++mi) {
      // stage (old orientation: row = lq*4+j, col = ni*16+l16)
#pragma unroll
      for (int ni = 0; ni < 4; ++ni)
#pragma unroll
        for (int j = 0; j < 4; ++j)
          ep[(lq * 4 + j) * 68 + ni * 16 + l16] = acc[mi][ni][j];
      int row = m0 + wr * 64 + mi * 16 + l16;   // transposed: row on l16
#pragma unroll
      for (int ni = 0; ni < 4; ++ni) {
        f32x4 v = *(const f32x4*)&ep[l16 * 68 + ni * 16 + lq * 4];
        int col = n0 + wc * 64 + ni * 16 + lq * 4;
        f32x4 bv = *(const f32x4*)&bias[col];
        v[0] += bv[0]; v[1] += bv[1]; v[2] += bv[2]; v[3] += bv[3];
        *(f32x4*)&C[(size_t)row * N + col] = v;
      }
    }
  } else {
    unsigned short* Qb = (unsigned short*)out0;
    unsigned short* Kb = (unsigned short*)out1;
    unsigned short* Vt = (unsigned short*)out2;
    int sel0 = n0 >> 10;
    if (sel0 < 2) {
      unsigned short* P = sel0 ? Kb : Qb;
      int hh = ((n0 >> 6) + wc) & 15;
#pragma unroll
      for (int mi = 0; mi < 4; ++mi) {
        // stage acc + bias (old orientation)
#pragma unroll
        for (int ni = 0; ni < 4; ++ni) {
          float bv = bias[n0 + wc * 64 + ni * 16 + l16];
#pragma unroll
          for (int j = 0; j < 4; ++j)
            ep[(lq * 4 + j) * 68 + ni * 16 + l16] = acc[mi][ni][j] + bv;
        }
        int rr = m0 + wr * 64 + mi * 16 + l16;  // token (transposed: on l16)
        int b_ = rr >> 11, s_ = rr & 2047;
        size_t pb = ((size_t)(b_ * NH + hh) * SS + s_) * 64;
        const float* tcp = tabc + ((size_t)rr << 5);
        const float* tsp = tabs + ((size_t)rr << 5);
#pragma unroll
        for (int ni = 0; ni < 4; ++ni) {
          f32x4 v = *(const f32x4*)&ep[l16 * 68 + ni * 16 + lq * 4];
          int d = ni * 16 + lq * 4;             // head-local dim (pairs local)
          int pfr = d >> 1;
          float c0 = tcp[pfr],     s0 = tsp[pfr];
          float c1 = tcp[pfr + 1], s1 = tsp[pfr + 1];
          ushort4v o;
          o[0] = f2bf(v[0] * c0 - v[1] * s0);
          o[1] = f2bf(v[0] * s0 + v[1] * c0);
          o[2] = f2bf(v[2] * c1 - v[3] * s1);
          o[3] = f2bf(v[2] * s1 + v[3] * c1);
          *(ushort4v*)&P[pb + d] = o;
        }
      }
    } else {
      // V path unchanged: already vectorized along s via Vt[b,h,d,s]
#pragma unroll
      for (int mi = 0; mi < 4; ++mi) {
        int row = m0 + wr * 64 + mi * 16 + lq * 4;
#pragma unroll
        for (int ni = 0; ni < 4; ++ni) {
          int col = n0 + wc * 64 + ni * 16 + l16;
          int hh = (col >> 6) & 15;
          int d = col & 63;
          float bv = bias[col];
          size_t p = ((size_t)((row >> 11) * NH + hh) * 64 + d) * SS + (row & 2047);
          ushort4v o;
#pragma unroll
          for (int j = 0; j < 4; ++j) o[j] = f2bf(acc[mi][ni][j] + bv);
          *(ushort4v*)&Vt[p] = o;
        }
      }
    }
  }
}

// ---------------- causal flash attention (R13/R15-measured-best, unchanged) --
__global__ __launch_bounds__(512) void k_attn(const unsigned short* __restrict__ Q,
                                              const unsigned short* __restrict__ K,
                                              const unsigned short* __restrict__ Vt,
                                              unsigned short* __restrict__ H) {
  __shared__ __align__(16) unsigned short Kbuf[2 * 4096];
  __shared__ __align__(16) unsigned short Vbuf[2 * 4096];

  int lin = blockIdx.x;          // 1024 blocks
  int bh = lin & 63;
  int g = 15 - (lin >> 6);       // granule 0..15 (128 q-rows), longest first
  int b = bh >> 4, h = bh & 15;
  int tid = threadIdx.x;
  int wid = tid >> 6, lane = tid & 63;
  int l16 = lane & 15, lq = lane >> 4;
  int sx = l16 & 7;              // read-side swizzle key (row&7)
  const unsigned short* Qh = Q + (size_t)bh * SS * 64;
  const unsigned short* Kh = K + (size_t)bh * SS * 64;
  const unsigned short* Vh = Vt + (size_t)bh * 64 * SS;

  int qbase = g * 128 + wid * 16;           // this wave's first q-row
  int qrow = qbase + l16;                   // this lane's q-row
  int ktmax = (qbase + 15) >> 6;            // last (diagonal) tile for this wave
  int ntk = 2 * g + 2;                      // tiles staged by the block

  short8 aq[2];
  {
    const unsigned short* qp = Qh + (size_t)qrow * 64 + lq * 8;
    aq[0] = *(const short8*)qp;
    aq[1] = *(const short8*)(qp + 32);
  }
  f32x4 o[4];
#pragma unroll
  for (int i = 0; i < 4; ++i) o[i] = (f32x4){0.f, 0.f, 0.f, 0.f};
  float lsum = 0.f;

  {
    int c = tid;
    int row = c >> 3, col = ((c & 7) ^ (row & 7)) << 3;
    gload_lds16(Kh + (size_t)row * 64 + col, &Kbuf[c * 8]);
    gload_lds16(Vh + (size_t)row * SS + col, &Vbuf[c * 8]);
  }
  __syncthreads();

  int cur = 0;
  for (int kt = 0; kt < ntk; ++kt) {
    if (kt + 1 < ntk) {
      int kb1 = (kt + 1) << 6;
      int nb_ = (cur ^ 1) * 4096;
      int c = tid;
      int row = c >> 3, col = ((c & 7) ^ (row & 7)) << 3;
      gload_lds16(Kh + (size_t)(kb1 + row) * 64 + col, &Kbuf[nb_ + c * 8]);
      gload_lds16(Vh + (size_t)row * SS + kb1 + col, &Vbuf[nb_ + c * 8]);
    }
    if (kt <= ktmax) {
      int kb = kt << 6;
      const unsigned short* Kb_ = &Kbuf[cur * 4096];
      const unsigned short* Vb_ = &Vbuf[cur * 4096];

      f32x4 sacc[4];
#pragma unroll
      for (int nb = 0; nb < 4; ++nb) {
        int r = nb * 16 + l16;
        short8 bk0 = *(const short8*)&Kb_[r * 64 + ((lq ^ sx) << 3)];
        short8 bk1 = *(const short8*)&Kb_[r * 64 + (((4 | lq) ^ sx) << 3)];
        f32x4 z = (f32x4){0.f, 0.f, 0.f, 0.f};
        z = MFMA16x32(bk0, aq[0], z);
        z = MFMA16x32(bk1, aq[1], z);
        sacc[nb] = z;
      }
      float sc[4][4];
#pragma unroll
      for (int nb = 0; nb < 4; ++nb)
#pragma unroll
        for (int j = 0; j < 4; ++j) sc[nb][j] = sacc[nb][j] * 0.18033688f;
      if (kt == ktmax) {
#pragma unroll
        for (int nb = 0; nb < 4; ++nb)
#pragma unroll
          for (int j = 0; j < 4; ++j) {
            int key = kb + nb * 16 + lq * 4 + j;
            if (key > qrow) sc[nb][j] = -1e30f;
          }
      }
      short4v pa[4];
#pragma unroll
      for (int nb = 0; nb < 4; ++nb) {
        float pv[4];
#pragma unroll
        for (int j = 0; j < 4; ++j) {
          float e;
          asm("v_exp_f32 %0, %1" : "=v"(e) : "v"(sc[nb][j]));
          lsum += e;
          pv[j] = e;
        }
        union { unsigned u[2]; short4v s4; } pk;
        asm("v_cvt_pk_bf16_f32 %0, %1, %2" : "=v"(pk.u[0]) : "v"(pv[0]), "v"(pv[1]));
        asm("v_cvt_pk_bf16_f32 %0, %1, %2" : "=v"(pk.u[1]) : "v"(pv[2]), "v"(pv[3]));
        pa[nb] = pk.s4;
      }
#pragma unroll
      for (int ni = 0; ni < 4; ++ni) {
        int row = ni * 16 + l16;
        f32x4 acc = o[ni];
#pragma unroll
        for (int nb = 0; nb < 4; ++nb) {
          int ch = (2 * nb + (lq >> 1)) ^ sx;
          short4v bv = *(const short4v*)&Vb_[row * 64 + ch * 8 + ((lq & 1) << 2)];
          acc = mfma_pv(pa[nb], bv, acc);
        }
        o[ni] = acc;
      }
    }
    __syncthreads();
    cur ^= 1;
  }

  float red = lsum;
  red += __shfl_xor(red, 16, 64);
  red += __shfl_xor(red, 32, 64);
  float inv[4];
#pragma unroll
  for (int j = 0; j < 4; ++j) {
    int src = (lane & 48) + ((lane >> 4) & 3) * 4 + j;
    inv[j] = 1.0f / __shfl(red, src, 64);
  }
#pragma unroll
  for (int ni = 0; ni < 4; ++ni) {
    int d = h * 64 + ni * 16 + l16;
#pragma unroll
    for (int j = 0; j < 4; ++j) {
      int s = qbase + lq * 4 + j;
      H[((size_t)(b * SS + s)) * 1024 + d] = f2bf(o[ni][j] * inv[j]);
    }
  }
}

extern "C" void kernel_launch(void* const* d_in, const int* in_sizes, int n_in,
                              void* d_out, int out_size, void* d_ws, size_t ws_size,
                              hipStream_t stream) {
  const float* x    = (const float*)d_in[0];
  const int*   pos  = (const int*)d_in[1];
  const float* Wqkv = (const float*)d_in[2];
  const float* bqkv = (const float*)d_in[3];
  const float* Wo   = (const float*)d_in[4];
  const float* bo   = (const float*)d_in[5];
  float* out = (float*)d_out;

  char* w = (char*)d_ws;
  unsigned short* x_bf    = (unsigned short*)(w + 0);          // 16 MB [8192][1024]
  unsigned short* h_bf    = x_bf;                              // alias (x dead after gemm1)
  unsigned short* wqkv_bf = (unsigned short*)(w + 16777216);   // 6 MB [3072][1024]
  unsigned short* wo_bf   = (unsigned short*)(w + 23068672);   // 2 MB [1024][1024]
  unsigned short* Qb      = (unsigned short*)(w + 25165824);   // 16 MB [64][2048][64]
  unsigned short* Kb      = (unsigned short*)(w + 41943040);   // 16 MB
  unsigned short* Vt      = (unsigned short*)(w + 58720256);   // 16 MB [64][64][2048]
  float* tabc             = (float*)(w + 75497472);            // 1 MB [8192][32]
  float* tabs             = (float*)(w + 76546048);            // 1 MB

  k_prep<<<13312, 256, 0, stream>>>(x, x_bf, Wqkv, wqkv_bf, Wo, wo_bf, pos, tabc, tabs);
  k_gemm3<1><<<768, 512, 0, stream>>>(x_bf, wqkv_bf, bqkv, Qb, Kb, Vt, tabc, tabs, TOK, 3072, DM);
  k_attn<<<1024, 512, 0, stream>>>(Qb, Kb, Vt, h_bf);
  k_gemm3<0><<<256, 512, 0, stream>>>(h_bf, wo_bf, bo, out, nullptr, nullptr, tabc, tabs, TOK, DM, DM);
}

// Round 17
// 182.611 us; speedup vs baseline: 1.0336x; 1.0336x over previous
//
#include <hip/hip_runtime.h>

#define DEV static __device__ __forceinline__

typedef __attribute__((ext_vector_type(8))) short short8;
typedef __attribute__((ext_vector_type(4))) short short4v;
typedef __attribute__((ext_vector_type(4))) float f32x4;
typedef __attribute__((ext_vector_type(4))) unsigned short ushort4v;
typedef __attribute__((ext_vector_type(4))) float float4v;

#define DM 1024
#define NH 16
#define HD 64
#define SS 2048
#define TOK 8192

DEV unsigned short f2bf(float f) {
  union { float f; unsigned u; } v; v.f = f;
  unsigned r = v.u + 0x7FFFu + ((v.u >> 16) & 1u);
  return (unsigned short)(r >> 16);
}
DEV float bf2f(unsigned short h) {
  union { unsigned u; float f; } v; v.u = ((unsigned)h) << 16;
  return v.f;
}

#define MFMA16x32(a, b, c) __builtin_amdgcn_mfma_f32_16x16x32_bf16((a), (b), (c), 0, 0, 0)

DEV f32x4 mfma_pv(short4v a, short4v b, f32x4 c) {
#if __has_builtin(__builtin_amdgcn_mfma_f32_16x16x16bf16_1k)
  return __builtin_amdgcn_mfma_f32_16x16x16bf16_1k(a, b, c, 0, 0, 0);
#else
  f32x4 d;
  asm("v_mfma_f32_16x16x16_bf16 %0, %1, %2, %3" : "=&v"(d) : "v"(a), "v"(b), "v"(c));
  return d;
#endif
}

DEV void gload_lds16(const unsigned short* g, unsigned short* l) {
  __builtin_amdgcn_global_load_lds(
      (const __attribute__((address_space(1))) void*)g,
      (__attribute__((address_space(3))) void*)l, 16, 0, 0);
}

// ------- fused prep: x cvt + Wqkv cvt + Wo cvt + RoPE tables (one launch) ----
__global__ __launch_bounds__(256) void k_prep(const float* __restrict__ x,
                                              unsigned short* __restrict__ x_bf,
                                              const float* __restrict__ Wqkv,
                                              unsigned short* __restrict__ wqkv_bf,
                                              const float* __restrict__ Wo,
                                              unsigned short* __restrict__ wo_bf,
                                              const int* __restrict__ pos,
                                              float* __restrict__ tc,
                                              float* __restrict__ ts) {
  int blk = blockIdx.x;
  if (blk < 8192) {
    int i = blk * 256 + threadIdx.x;
    float4v v = ((const float4v*)x)[i];
    ushort4v o;
    o[0] = f2bf(v[0]); o[1] = f2bf(v[1]); o[2] = f2bf(v[2]); o[3] = f2bf(v[3]);
    ((ushort4v*)x_bf)[i] = o;
  } else if (blk < 11264) {
    int i = (blk - 8192) * 256 + threadIdx.x;
    float4v v = ((const float4v*)Wqkv)[i];
    ushort4v o;
    o[0] = f2bf(v[0]); o[1] = f2bf(v[1]); o[2] = f2bf(v[2]); o[3] = f2bf(v[3]);
    ((ushort4v*)wqkv_bf)[i] = o;
  } else if (blk < 12288) {
    int i = (blk - 11264) * 256 + threadIdx.x;
    float4v v = ((const float4v*)Wo)[i];
    ushort4v o;
    o[0] = f2bf(v[0]); o[1] = f2bf(v[1]); o[2] = f2bf(v[2]); o[3] = f2bf(v[3]);
    ((ushort4v*)wo_bf)[i] = o;
  } else {
    int i = (blk - 12288) * 256 + threadIdx.x;   // B*S*32 total
    int t = i >> 5, fi = i & 31;
    float p = (float)pos[t];
    float inv = powf(10000.0f, -(float)fi / 32.0f);
    float a = p * inv;
    float sv, cv;
    sincosf(a, &sv, &cv);
    tc[i] = cv;
    ts[i] = sv;
  }
}

// ---------------- bf16 GEMM, B^T layout, 3-stage counted-vmcnt pipeline -----
// (R13/R15-measured-best: BM=256, BN=128, BK=64, 512 thr, 3 rotating
//  buffers, counted vmcnt(6), 0-conflict LDS, m-chunk XCD swizzle,
//  R10-style scatter epilogue with fused RoPE — R16's transposed epilogue
//  regressed (8-way LDS read conflict), reverted.)
// MODE 0: out0 = fp32 [M][N]
// MODE 1: qkv scatter + FUSED ROPE on Q,K; out2=Vt [b,h,d,s]
template <int MODE>
__global__ __launch_bounds__(512) void k_gemm3(
    const unsigned short* __restrict__ A, const unsigned short* __restrict__ Bm,
    const float* __restrict__ bias, void* __restrict__ out0, void* __restrict__ out1,
    void* __restrict__ out2, const float* __restrict__ tabc,
    const float* __restrict__ tabs, int M, int N, int K) {
  __shared__ __align__(16) unsigned short Abuf[3][256 * 64];   // 96 KB
  __shared__ __align__(16) unsigned short Bbuf[3][128 * 64];   // 48 KB
  const int tid = threadIdx.x;
  const int wid = tid >> 6, lane = tid & 63;
  const int l16 = lane & 15, lq = lane >> 4;
  const int wr = wid >> 1, wc = wid & 1;
  const int r8 = lane >> 3, c8 = lane & 7;    // staging: row-in-octet, chunk
  const int NT = K >> 6;
  const int sx = l16 & 7;                     // read-side swizzle key

  // m-chunk XCD swizzle (R6): xcd = bid&7 owns contiguous m-range, n-fastest.
  const int gx = N >> 7;
  const int nwg = gx * (M >> 8);
  const int chunk = nwg >> 3;
  const int bid = blockIdx.x;
  const int virt = (bid & 7) * chunk + (bid >> 3);
  const int m0 = (virt / gx) << 8;
  const int n0 = (virt % gx) << 7;

#define STAGE_G3(T, BSEL)                                                           \
  {                                                                                 \
    int k0_ = (T) << 6;                                                             \
    unsigned short* ab_ = Abuf[BSEL];                                               \
    unsigned short* bb_ = Bbuf[BSEL];                                               \
    _Pragma("unroll")                                                               \
    for (int i_ = 0; i_ < 4; ++i_) {                                                \
      int c_ = wid * 4 + i_;                                                        \
      gload_lds16(A + (size_t)(m0 + c_ * 8 + r8) * K + k0_ + ((c8 ^ r8) << 3),      \
                  &ab_[c_ * 512]);                                                  \
    }                                                                               \
    _Pragma("unroll")                                                               \
    for (int i_ = 0; i_ < 2; ++i_) {                                                \
      int c_ = wid * 2 + i_;                                                        \
      gload_lds16(Bm + (size_t)(n0 + c_ * 8 + r8) * K + k0_ + ((c8 ^ r8) << 3),     \
                  &bb_[c_ * 512]);                                                  \
    }                                                                               \
  }

  f32x4 acc[4][4];
#pragma unroll
  for (int i = 0; i < 4; i++)
#pragma unroll
    for (int j = 0; j < 4; j++) acc[i][j] = (f32x4){0.f, 0.f, 0.f, 0.f};

  STAGE_G3(0, 0)
  STAGE_G3(1, 1)
  asm volatile("s_waitcnt vmcnt(6)" ::: "memory");
  __builtin_amdgcn_s_barrier();
  __builtin_amdgcn_sched_barrier(0);

  int cb = 0, sb = 2;
  for (int t = 0; t < NT; ++t) {
    if (t + 2 < NT) STAGE_G3(t + 2, sb)
    const unsigned short* Ab = Abuf[cb];
    const unsigned short* Bb = Bbuf[cb];
#pragma unroll
    for (int kk = 0; kk < 2; ++kk) {
      int sw0 = ((kk * 4 + lq) ^ sx) << 3;
      short8 af[4], bfr[4];
#pragma unroll
      for (int mi = 0; mi < 4; ++mi)
        af[mi] = *(const short8*)&Ab[(wr * 64 + mi * 16 + l16) * 64 + sw0];
#pragma unroll
      for (int ni = 0; ni < 4; ++ni)
        bfr[ni] = *(const short8*)&Bb[(wc * 64 + ni * 16 + l16) * 64 + sw0];
#pragma unroll
      for (int mi = 0; mi < 4; ++mi)
#pragma unroll
        for (int ni = 0; ni < 4; ++ni)
          acc[mi][ni] = MFMA16x32(af[mi], bfr[ni], acc[mi][ni]);
    }
    if (t + 1 < NT) {
      if (t + 3 <= NT) {
        asm volatile("s_waitcnt vmcnt(6)" ::: "memory");
      } else {
        asm volatile("s_waitcnt vmcnt(0)" ::: "memory");
      }
      __builtin_amdgcn_s_barrier();
      __builtin_amdgcn_sched_barrier(0);
    }
    cb = (cb == 2) ? 0 : cb + 1;
    sb = (sb == 2) ? 0 : sb + 1;
  }
#undef STAGE_G3

  if (MODE == 0) {
    float* C = (float*)out0;
#pragma unroll
    for (int mi = 0; mi < 4; ++mi) {
      int row = m0 + wr * 64 + mi * 16 + lq * 4;
#pragma unroll
      for (int ni = 0; ni < 4; ++ni) {
        int col = n0 + wc * 64 + ni * 16 + l16;
        float bv = bias[col];
#pragma unroll
        for (int j = 0; j < 4; ++j)
          C[(size_t)(row + j) * N + col] = acc[mi][ni][j] + bv;
      }
    }
  } else {
    unsigned short* Qb = (unsigned short*)out0;
    unsigned short* Kb = (unsigned short*)out1;
    unsigned short* Vt = (unsigned short*)out2;
    int sel0 = n0 >> 10;
#pragma unroll
    for (int mi = 0; mi < 4; ++mi) {
      int row = m0 + wr * 64 + mi * 16 + lq * 4;
#pragma unroll
      for (int ni = 0; ni < 4; ++ni) {
        int col = n0 + wc * 64 + ni * 16 + l16;
        int hh = (col >> 6) & 15;
        int d = col & 63;
        float bv = bias[col];
        if (sel0 < 2) {
          unsigned short* P = sel0 ? Kb : Qb;
          int pfr = d >> 1;
          size_t p = ((size_t)((row >> 11) * NH + hh) * SS + (row & 2047)) * 64 + d;
#pragma unroll
          for (int j = 0; j < 4; ++j) {
            float val = acc[mi][ni][j] + bv;
            float part = __shfl_xor(val, 1, 64);
            int rr = row + j;
            float cv = tabc[((size_t)rr << 5) + pfr];
            float sv = tabs[((size_t)rr << 5) + pfr];
            float outv = (d & 1) ? (part * sv + val * cv)
                                 : (val * cv - part * sv);
            P[p + (size_t)j * 64] = f2bf(outv);
          }
        } else {
          size_t p = ((size_t)((row >> 11) * NH + hh) * 64 + d) * SS + (row & 2047);
          ushort4v o;
#pragma unroll
          for (int j = 0; j < 4; ++j) o[j] = f2bf(acc[mi][ni][j] + bv);
          *(ushort4v*)&Vt[p] = o;
        }
      }
    }
  }
}

// ---------------- causal flash attention, swapped-QK in-register softmax ----
// (R13/R15 structure: q-granule 128 rows, 8 waves x 16 q-rows, 1024 blocks,
//  longest first.)
// NEW: 3-buffer rotating K/V staging with COUNTED vmcnt (same recipe as
// k_gemm3): stage tile t+2 into buf[(t+2)%3] (readers passed the iter t-1
// barrier); end-of-iter s_waitcnt vmcnt(2) leaves this iter's 2 loads in
// flight while guaranteeing tile t+1 is complete. Removes the per-tile
// full vmcnt(0) drain that __syncthreads() imposed. LDS 48 KB.
__global__ __launch_bounds__(512) void k_attn(const unsigned short* __restrict__ Q,
                                              const unsigned short* __restrict__ K,
                                              const unsigned short* __restrict__ Vt,
                                              unsigned short* __restrict__ H) {
  __shared__ __align__(16) unsigned short Kbuf[3 * 4096];
  __shared__ __align__(16) unsigned short Vbuf[3 * 4096];

  int lin = blockIdx.x;          // 1024 blocks
  int bh = lin & 63;
  int g = 15 - (lin >> 6);       // granule 0..15 (128 q-rows), longest first
  int b = bh >> 4, h = bh & 15;
  int tid = threadIdx.x;
  int wid = tid >> 6, lane = tid & 63;
  int l16 = lane & 15, lq = lane >> 4;
  int sx = l16 & 7;              // read-side swizzle key (row&7)
  const unsigned short* Qh = Q + (size_t)bh * SS * 64;
  const unsigned short* Kh = K + (size_t)bh * SS * 64;
  const unsigned short* Vh = Vt + (size_t)bh * 64 * SS;

  int qbase = g * 128 + wid * 16;           // this wave's first q-row
  int qrow = qbase + l16;                   // this lane's q-row
  int ktmax = (qbase + 15) >> 6;            // last (diagonal) tile for this wave
  int ntk = 2 * g + 2;                      // tiles staged by the block

  // staging geometry: 512 threads cover 512 16B cells per 8KB tile
  const int srow = tid >> 3;
  const int scol = ((tid & 7) ^ (srow & 7)) << 3;

#define STAGE_ATT(T, BSEL)                                                      \
  {                                                                             \
    int kb_ = (T) << 6;                                                         \
    gload_lds16(Kh + (size_t)(kb_ + srow) * 64 + scol,                          \
                &Kbuf[(BSEL) * 4096 + tid * 8]);                                \
    gload_lds16(Vh + (size_t)srow * SS + kb_ + scol,                            \
                &Vbuf[(BSEL) * 4096 + tid * 8]);                                \
  }

  // Q as B-fragments (col=l16 -> q-row)
  short8 aq[2];
  {
    const unsigned short* qp = Qh + (size_t)qrow * 64 + lq * 8;
    aq[0] = *(const short8*)qp;
    aq[1] = *(const short8*)(qp + 32);
  }
  f32x4 o[4];
#pragma unroll
  for (int i = 0; i < 4; ++i) o[i] = (f32x4){0.f, 0.f, 0.f, 0.f};
  float lsum = 0.f;

  // prologue: tiles 0,1 in flight (4 loads/thread); wait tile 0 (2 outstanding)
  STAGE_ATT(0, 0)
  STAGE_ATT(1, 1)
  asm volatile("s_waitcnt vmcnt(2)" ::: "memory");
  __builtin_amdgcn_s_barrier();
  __builtin_amdgcn_sched_barrier(0);

  int cb = 0, sb = 2;
  for (int kt = 0; kt < ntk; ++kt) {
    if (kt + 2 < ntk) STAGE_ATT(kt + 2, sb)
    if (kt <= ktmax) {
      int kb = kt << 6;
      const unsigned short* Kb_ = &Kbuf[cb * 4096];
      const unsigned short* Vb_ = &Vbuf[cb * 4096];

      // swapped QK^T: sacc[nb] = C[key][q], key = nb*16 + lq*4 + j, q = l16
      f32x4 sacc[4];
#pragma unroll
      for (int nb = 0; nb < 4; ++nb) {
        int r = nb * 16 + l16;
        short8 bk0 = *(const short8*)&Kb_[r * 64 + ((lq ^ sx) << 3)];
        short8 bk1 = *(const short8*)&Kb_[r * 64 + (((4 | lq) ^ sx) << 3)];
        f32x4 z = (f32x4){0.f, 0.f, 0.f, 0.f};
        z = MFMA16x32(bk0, aq[0], z);
        z = MFMA16x32(bk1, aq[1], z);
        sacc[nb] = z;
      }
      // scale (with log2e folded), mask, exp2, accumulate, pack
      float sc[4][4];
#pragma unroll
      for (int nb = 0; nb < 4; ++nb)
#pragma unroll
        for (int j = 0; j < 4; ++j) sc[nb][j] = sacc[nb][j] * 0.18033688f;
      if (kt == ktmax) {   // diagonal tile (wave-uniform branch)
#pragma unroll
        for (int nb = 0; nb < 4; ++nb)
#pragma unroll
          for (int j = 0; j < 4; ++j) {
            int key = kb + nb * 16 + lq * 4 + j;
            if (key > qrow) sc[nb][j] = -1e30f;
          }
      }
      short4v pa[4];
#pragma unroll
      for (int nb = 0; nb < 4; ++nb) {
        float pv[4];
#pragma unroll
        for (int j = 0; j < 4; ++j) {
          float e;
          asm("v_exp_f32 %0, %1" : "=v"(e) : "v"(sc[nb][j]));
          lsum += e;
          pv[j] = e;
        }
        union { unsigned u[2]; short4v s4; } pk;
        asm("v_cvt_pk_bf16_f32 %0, %1, %2" : "=v"(pk.u[0]) : "v"(pv[0]), "v"(pv[1]));
        asm("v_cvt_pk_bf16_f32 %0, %1, %2" : "=v"(pk.u[1]) : "v"(pv[2]), "v"(pv[3]));
        pa[nb] = pk.s4;
      }
      // PV: O[q][d] += P[q][k] * V[k][d]; V from Vt rows (d on l16)
#pragma unroll
      for (int ni = 0; ni < 4; ++ni) {
        int row = ni * 16 + l16;
        f32x4 acc = o[ni];
#pragma unroll
        for (int nb = 0; nb < 4; ++nb) {
          int ch = (2 * nb + (lq >> 1)) ^ sx;
          short4v bv = *(const short4v*)&Vb_[row * 64 + ch * 8 + ((lq & 1) << 2)];
          acc = mfma_pv(pa[nb], bv, acc);
        }
        o[ni] = acc;
      }
    }
    if (kt + 1 < ntk) {
      if (kt + 2 < ntk) {
        asm volatile("s_waitcnt vmcnt(2)" ::: "memory");
      } else {
        asm volatile("s_waitcnt vmcnt(0)" ::: "memory");
      }
      __builtin_amdgcn_s_barrier();
      __builtin_amdgcn_sched_barrier(0);
    }
    cb = (cb == 2) ? 0 : cb + 1;
    sb = (sb == 2) ? 0 : sb + 1;
  }
#undef STAGE_ATT

  // reduce lsum over the 4 lq-lanes, redistribute to output rows
  float red = lsum;
  red += __shfl_xor(red, 16, 64);
  red += __shfl_xor(red, 32, 64);
  float inv[4];
#pragma unroll
  for (int j = 0; j < 4; ++j) {
    int src = (lane & 48) + ((lane >> 4) & 3) * 4 + j;
    inv[j] = 1.0f / __shfl(red, src, 64);
  }
#pragma unroll
  for (int ni = 0; ni < 4; ++ni) {
    int d = h * 64 + ni * 16 + l16;
#pragma unroll
    for (int j = 0; j < 4; ++j) {
      int s = qbase + lq * 4 + j;
      H[((size_t)(b * SS + s)) * 1024 + d] = f2bf(o[ni][j] * inv[j]);
    }
  }
}

extern "C" void kernel_launch(void* const* d_in, const int* in_sizes, int n_in,
                              void* d_out, int out_size, void* d_ws, size_t ws_size,
                              hipStream_t stream) {
  const float* x    = (const float*)d_in[0];
  const int*   pos  = (const int*)d_in[1];
  const float* Wqkv = (const float*)d_in[2];
  const float* bqkv = (const float*)d_in[3];
  const float* Wo   = (const float*)d_in[4];
  const float* bo   = (const float*)d_in[5];
  float* out = (float*)d_out;

  char* w = (char*)d_ws;
  unsigned short* x_bf    = (unsigned short*)(w + 0);          // 16 MB [8192][1024]
  unsigned short* h_bf    = x_bf;                              // alias (x dead after gemm1)
  unsigned short* wqkv_bf = (unsigned short*)(w + 16777216);   // 6 MB [3072][1024]
  unsigned short* wo_bf   = (unsigned short*)(w + 23068672);   // 2 MB [1024][1024]
  unsigned short* Qb      = (unsigned short*)(w + 25165824);   // 16 MB [64][2048][64]
  unsigned short* Kb      = (unsigned short*)(w + 41943040);   // 16 MB
  unsigned short* Vt      = (unsigned short*)(w + 58720256);   // 16 MB [64][64][2048]
  float* tabc             = (float*)(w + 75497472);            // 1 MB [8192][32]
  float* tabs             = (float*)(w + 76546048);            // 1 MB

  k_prep<<<13312, 256, 0, stream>>>(x, x_bf, Wqkv, wqkv_bf, Wo, wo_bf, pos, tabc, tabs);
  k_gemm3<1><<<768, 512, 0, stream>>>(x_bf, wqkv_bf, bqkv, Qb, Kb, Vt, tabc, tabs, TOK, 3072, DM);
  k_attn<<<1024, 512, 0, stream>>>(Qb, Kb, Vt, h_bf);
  k_gemm3<0><<<256, 512, 0, stream>>>(h_bf, wo_bf, bo, out, nullptr, nullptr, tabc, tabs, TOK, DM, DM);
}